// Round 4
// baseline (402.495 us; speedup 1.0000x reference)
//
#include <hip/hip_runtime.h>
#include <math.h>

constexpr int Nn  = 65536;    // nodes
constexpr int Ne  = 1048576;  // edges
constexpr int Bg  = 256;      // graphs
constexpr int DIN = 32;
constexpr int D   = 64;

constexpr int NB   = 256;     // dst buckets (dst>>8)
constexpr int BCAP = 6144;    // bucket stream capacity (mean 4096, +36 sigma)

typedef __attribute__((ext_vector_type(8))) short bf16x8;
typedef __attribute__((ext_vector_type(8))) unsigned short u16x8;
typedef __attribute__((ext_vector_type(4))) float f32x4;

__device__ __forceinline__ float sigf(float x) { return 1.0f / (1.0f + expf(-x)); }

// ---- bf16 split helpers (RNE) ----
__device__ __forceinline__ unsigned short bf16_rne(float f) {
  unsigned u = __float_as_uint(f);
  unsigned r = u + 0x7FFFu + ((u >> 16) & 1u);
  return (unsigned short)(r >> 16);
}
__device__ __forceinline__ float bf16_tof(unsigned short h) {
  return __uint_as_float(((unsigned)h) << 16);
}
__device__ __forceinline__ void split2(float f, unsigned short& hi, unsigned short& lo) {
  hi = bf16_rne(f);
  lo = bf16_rne(f - bf16_tof(hi));
}
__device__ __forceinline__ float recon(unsigned short hi, unsigned short lo) {
  return bf16_tof(hi) + bf16_tof(lo);
}

#define MFMA(a, b, c) __builtin_amdgcn_mfma_f32_16x16x32_bf16(a, b, c, 0, 0, 0)

// ---------------------------------------------------------------------------
// Prep.  GRU weights chunk-major (5 chunks x 12nt x 64lane x 8j / plane):
//   chunks 0,1 = Wfold = Wih[:, :64] @ W_conv   (fused conv-linear)
//   chunk  2   = Wih[:, 64:96]  (x part)
//   chunks 3,4 = Whh
// Also: W_mlp pack, LSTM/W1 transposes, graphptr, rp[Nn], vfold.
// ---------------------------------------------------------------------------
__global__ void k_prepw(const float* __restrict__ W_mlp, const float* __restrict__ W_conv,
                        const float* __restrict__ gWih, const float* __restrict__ gWhh,
                        const float* __restrict__ b_conv,
                        const float* __restrict__ lW_ih, const float* __restrict__ lW_hh,
                        const float* __restrict__ W1,
                        unsigned short* __restrict__ mlp_h, unsigned short* __restrict__ mlp_l,
                        unsigned short* __restrict__ gw_h,  unsigned short* __restrict__ gw_l,
                        float* __restrict__ WihT, float* __restrict__ WhhT,
                        float* __restrict__ W1T, float* __restrict__ vfold,
                        const int* __restrict__ batch, int* __restrict__ gp,
                        int* __restrict__ rp) {
  int idx = blockIdx.x * 256 + threadIdx.x;
  if (idx < 30720) {  // GRU weights, chunk-major
    int c = idx / 6144, rem = idx % 6144;
    int nt = rem >> 9, lane = (rem >> 3) & 63, j = rem & 7;
    int n = nt * 16 + (lane & 15);
    int kk = c * 32 + (lane >> 4) * 8 + j;   // for c<3: k index into [S|x]
    float v;
    if (c < 2) {        // Wfold[n][kk] = sum_o Wih[n][o] * W_conv[o][kk]
      float s = 0.f;
      for (int o = 0; o < 64; ++o) s = fmaf(gWih[n * 96 + o], W_conv[o * 64 + kk], s);
      v = s;
    } else if (c == 2) {
      v = gWih[n * 96 + kk];                 // kk in 64..95 (x columns)
    } else {
      v = gWhh[n * 64 + (c - 3) * 32 + (lane >> 4) * 8 + j];
    }
    unsigned short hi, lo; split2(v, hi, lo);
    gw_h[idx] = hi; gw_l[idx] = lo;
    return;
  }
  if (idx < 32768) {  // W_mlp (KS=1)
    int lp = idx - 30720;
    int nt = lp >> 9, lane = (lp >> 3) & 63, j = lp & 7;
    int n = nt * 16 + (lane & 15);
    unsigned short hi, lo;
    split2(W_mlp[n * 32 + (lane >> 4) * 8 + j], hi, lo);
    mlp_h[lp] = hi; mlp_l[lp] = lo;
    return;
  }
  int t = idx - 32768;
  if (t < 32768) {                 // lstm W_ih [256][128] -> WihT [128][256]
    int row = t / 128, k = t % 128;
    WihT[k * 256 + row] = lW_ih[t];
  } else if (t < 49152) {          // lstm W_hh [256][64] -> WhhT [64][256]
    int j = t - 32768;
    int row = j / 64, k = j % 64;
    WhhT[k * 256 + row] = lW_hh[j];
  } else if (t < 57344) {          // W1 [64][128] -> W1T [128][64]
    int j = t - 49152;
    int row = j / 128, k = j % 128;
    W1T[k * 64 + row] = W1[j];
  } else if (t < 57344 + Bg + 1) { // graphptr + rp[Nn]
    int g = t - 57344;
    if (g == 0) rp[Nn] = Ne;
    int lo = 0, hi = Nn;
    while (lo < hi) {
      int mid = (lo + hi) >> 1;
      if (batch[mid] < g) lo = mid + 1; else hi = mid;
    }
    gp[g] = lo;
  } else if (t < 57344 + 257 + 192) { // vfold[192]
    int g = t - 57344 - 257;
    float s = 0.f;
    for (int o = 0; o < 64; ++o) s = fmaf(gWih[g * 96 + o], b_conv[o], s);
    vfold[g] = s;
  }
}

// ---------------------------------------------------------------------------
// conv1: h = x @ W_mlp^T + b  (K=32, N=64). Splits x in-kernel; also fills
// inp96 x-columns (64..95).  h stored as planes only.
// ---------------------------------------------------------------------------
__global__ __launch_bounds__(256) void k_conv1(const float* __restrict__ x,
                                               const unsigned short* __restrict__ Wh,
                                               const unsigned short* __restrict__ Wl,
                                               const float* __restrict__ bias,
                                               unsigned short* __restrict__ hph,
                                               unsigned short* __restrict__ hpl,
                                               unsigned short* __restrict__ Aih,
                                               unsigned short* __restrict__ Ail) {
  int wave = threadIdx.x >> 6, lane = threadIdx.x & 63;
  int quad = lane >> 4;
  int n0w = blockIdx.x * 64 + wave * 16;
  int rowA = n0w + (lane & 15);
  const float4* xp = (const float4*)&x[(size_t)rowA * 32 + quad * 8];
  float4 xa = xp[0], xb = xp[1];
  float xv[8] = {xa.x, xa.y, xa.z, xa.w, xb.x, xb.y, xb.z, xb.w};
  bf16x8 ah, al;
#pragma unroll
  for (int j = 0; j < 8; ++j) {
    unsigned short hi, lo; split2(xv[j], hi, lo);
    ah[j] = (short)hi; al[j] = (short)lo;
  }
  *(bf16x8*)&Aih[(size_t)rowA * 96 + 64 + quad * 8] = ah;
  *(bf16x8*)&Ail[(size_t)rowA * 96 + 64 + quad * 8] = al;

  f32x4 acc[4] = {};
#pragma unroll
  for (int nt = 0; nt < 4; ++nt) {
    bf16x8 bh = *(const bf16x8*)&Wh[(nt * 64 + lane) * 8];
    bf16x8 bl = *(const bf16x8*)&Wl[(nt * 64 + lane) * 8];
    acc[nt] = MFMA(ah, bh, acc[nt]);
    acc[nt] = MFMA(ah, bl, acc[nt]);
    acc[nt] = MFMA(al, bh, acc[nt]);
  }
  int col0 = lane & 15;
#pragma unroll
  for (int nt = 0; nt < 4; ++nt) {
    float bv = bias[nt * 16 + col0];
#pragma unroll
    for (int r = 0; r < 4; ++r) {
      int node = n0w + quad * 4 + r;
      float v = acc[nt][r] + bv;
      size_t o = (size_t)node * 64 + nt * 16 + col0;
      unsigned short hi, lo; split2(v, hi, lo);
      hph[o] = hi; hpl[o] = lo;
    }
  }
}

// ---------------------------------------------------------------------------
// Aggregate v4: one wave per node; lane l owns edge-slot (l>>3) and columns
// (l&7)*8..+7.  Each load instruction is u16x8 (16 B/lane, 1 KB/wave) and
// covers 8 EDGES at once -> 8x fewer gather instructions than v3, no shfl
// broadcast chain, 16 lines in flight per wave (2-deep unroll).  Edge-slot
// partial sums are combined by a fixed-order xor-shuffle tree.
// ---------------------------------------------------------------------------
__global__ __launch_bounds__(256) void k_aggr(const unsigned short* __restrict__ Hh,
                                              const int* __restrict__ rp,
                                              const int* __restrict__ srcs,
                                              unsigned short* __restrict__ Sh,
                                              unsigned short* __restrict__ Sl) {
  int wave = threadIdx.x >> 6, lane = threadIdx.x & 63;
  int node = blockIdx.x * 4 + wave;
  int s = rp[node], e = rp[node + 1];
  int n = e - s;
  const int* sp = srcs + s;
  int col8 = (lane & 7) * 8;
  int eslot = lane >> 3;
  float acc8[8] = {};
  int k = 0;
  for (; k + 16 <= n; k += 16) {
    int sA = sp[k + eslot];
    int sB = sp[k + 8 + eslot];
    u16x8 a = *(const u16x8*)&Hh[(size_t)sA * 64 + col8];
    u16x8 b = *(const u16x8*)&Hh[(size_t)sB * 64 + col8];
#pragma unroll
    for (int j = 0; j < 8; ++j) acc8[j] += bf16_tof(a[j]);
#pragma unroll
    for (int j = 0; j < 8; ++j) acc8[j] += bf16_tof(b[j]);
  }
  for (; k < n; k += 8) {
    if (k + eslot < n) {
      int sA = sp[k + eslot];
      u16x8 a = *(const u16x8*)&Hh[(size_t)sA * 64 + col8];
#pragma unroll
      for (int j = 0; j < 8; ++j) acc8[j] += bf16_tof(a[j]);
    }
  }
  // combine the 8 edge-slot partials (fixed-order tree over lanes l^8,l^16,l^32)
#pragma unroll
  for (int m = 8; m <= 32; m <<= 1) {
#pragma unroll
    for (int j = 0; j < 8; ++j) acc8[j] += __shfl_xor(acc8[j], m);
  }
  if (lane < 8) {
    u16x8 hv, lv;
#pragma unroll
    for (int j = 0; j < 8; ++j) {
      unsigned short hi, lo; split2(acc8[j], hi, lo);
      hv[j] = hi; lv[j] = lo;
    }
    *(u16x8*)&Sh[(size_t)node * 64 + col8] = hv;
    *(u16x8*)&Sl[(size_t)node * 64 + col8] = lv;
  }
}

// ---------------------------------------------------------------------------
// Fused GRU v9: gather moved out to k_aggr; chunks 0,1 read the S planes
// (Sh/Sl) exactly like the Whh chunks read Hh/Hl.  Keeps the proven
// 5-chunk double-buffered-LDS K-loop and epilogue.
// ---------------------------------------------------------------------------
__global__ __launch_bounds__(256, 2) void k_gru(const unsigned short* __restrict__ Aih,
                                                const unsigned short* __restrict__ Ail,
                                                const unsigned short* __restrict__ Hh,
                                                const unsigned short* __restrict__ Hl,
                                                const unsigned short* __restrict__ Sh,
                                                const unsigned short* __restrict__ Sl,
                                                const unsigned short* __restrict__ gw_h,
                                                const unsigned short* __restrict__ gw_l,
                                                const float* __restrict__ b_ih,
                                                const float* __restrict__ b_hh,
                                                const float* __restrict__ vfold,
                                                const int* __restrict__ rp,
                                                unsigned short* __restrict__ nph,
                                                unsigned short* __restrict__ npl) {
  __shared__ unsigned short sW[2][12288];  // per buf: hi[0..6143] | lo[6144..]
  int tid = threadIdx.x;
  int wave = tid >> 6, lane = tid & 63;
  int quad = lane >> 4;
  int n0w = blockIdx.x * 128 + wave * 32;
  int rowA0 = n0w + (lane & 15);          // tile0 A-row; tile1 = +16

  f32x4 acc0[12] = {}, acc1[12] = {};     // gi r,z,n (gh r,z folded into 0..7)
  f32x4 aN0[4] = {}, aN1[4] = {};         // gh n-gate

  // prologue: weights chunk 0
  bf16x8 gvh[3], gvl[3];
#pragma unroll
  for (int j = 0; j < 3; ++j) {
    gvh[j] = *(const bf16x8*)&gw_h[(tid + j * 256) * 8];
    gvl[j] = *(const bf16x8*)&gw_l[(tid + j * 256) * 8];
  }
#pragma unroll
  for (int j = 0; j < 3; ++j) {
    *(bf16x8*)&sW[0][(tid + j * 256) * 8] = gvh[j];
    *(bf16x8*)&sW[0][6144 + (tid + j * 256) * 8] = gvl[j];
  }
  __syncthreads();

#pragma unroll
  for (int c = 0; c < 5; ++c) {
    const int buf = c & 1;
    if (c < 4) {  // prefetch chunk c+1 weights
#pragma unroll
      for (int j = 0; j < 3; ++j) {
        gvh[j] = *(const bf16x8*)&gw_h[(c + 1) * 6144 + (tid + j * 256) * 8];
        gvl[j] = *(const bf16x8*)&gw_l[(c + 1) * 6144 + (tid + j * 256) * 8];
      }
    }
    // A fragments
    bf16x8 a0h, a0l, a1h, a1l;
    if (c < 2) {            // aggregated S planes from k_aggr
      size_t b0 = (size_t)rowA0 * 64 + c * 32 + quad * 8;
      size_t b1 = (size_t)(rowA0 + 16) * 64 + c * 32 + quad * 8;
      a0h = *(const bf16x8*)&Sh[b0]; a0l = *(const bf16x8*)&Sl[b0];
      a1h = *(const bf16x8*)&Sh[b1]; a1l = *(const bf16x8*)&Sl[b1];
    } else if (c == 2) {    // x columns from conv1 prep
      size_t b0 = (size_t)rowA0 * 96 + 64 + quad * 8;
      size_t b1 = (size_t)(rowA0 + 16) * 96 + 64 + quad * 8;
      a0h = *(const bf16x8*)&Aih[b0]; a0l = *(const bf16x8*)&Ail[b0];
      a1h = *(const bf16x8*)&Aih[b1]; a1l = *(const bf16x8*)&Ail[b1];
    } else {                // h planes (Whh chunks)
      size_t b0 = (size_t)rowA0 * 64 + (c - 3) * 32 + quad * 8;
      size_t b1 = (size_t)(rowA0 + 16) * 64 + (c - 3) * 32 + quad * 8;
      a0h = *(const bf16x8*)&Hh[b0]; a0l = *(const bf16x8*)&Hl[b0];
      a1h = *(const bf16x8*)&Hh[b1]; a1l = *(const bf16x8*)&Hl[b1];
    }
    const unsigned short* sw = sW[buf];
#pragma unroll
    for (int nt = 0; nt < 12; ++nt) {
      bf16x8 bh = *(const bf16x8*)&sw[(nt * 64 + lane) * 8];
      bf16x8 bl = *(const bf16x8*)&sw[6144 + (nt * 64 + lane) * 8];
      if (c < 3 || nt < 8) {
        acc0[nt] = MFMA(a0h, bh, acc0[nt]);
        acc0[nt] = MFMA(a0h, bl, acc0[nt]);
        acc0[nt] = MFMA(a0l, bh, acc0[nt]);
        acc1[nt] = MFMA(a1h, bh, acc1[nt]);
        acc1[nt] = MFMA(a1h, bl, acc1[nt]);
        acc1[nt] = MFMA(a1l, bh, acc1[nt]);
      } else {
        aN0[nt - 8] = MFMA(a0h, bh, aN0[nt - 8]);
        aN0[nt - 8] = MFMA(a0h, bl, aN0[nt - 8]);
        aN0[nt - 8] = MFMA(a0l, bh, aN0[nt - 8]);
        aN1[nt - 8] = MFMA(a1h, bh, aN1[nt - 8]);
        aN1[nt - 8] = MFMA(a1h, bl, aN1[nt - 8]);
        aN1[nt - 8] = MFMA(a1l, bh, aN1[nt - 8]);
      }
    }
    if (c < 4) {
#pragma unroll
      for (int j = 0; j < 3; ++j) {
        *(bf16x8*)&sW[1 - buf][(tid + j * 256) * 8] = gvh[j];
        *(bf16x8*)&sW[1 - buf][6144 + (tid + j * 256) * 8] = gvl[j];
      }
    }
    __syncthreads();
  }

  // epilogue: GRU nonlinearity + deg*vfold (folded conv bias) + plane store
  int col0 = lane & 15;
#pragma unroll
  for (int tile = 0; tile < 2; ++tile) {
    int nb = n0w + tile * 16;
#pragma unroll
    for (int r = 0; r < 4; ++r) {
      int node = nb + quad * 4 + r;
      float degf = (float)(rp[node + 1] - rp[node]);
#pragma unroll
      for (int nt = 0; nt < 4; ++nt) {
        int g = nt * 16 + col0;
        size_t o = (size_t)node * 64 + g;
        float br  = b_ih[g] + b_hh[g] + degf * vfold[g];
        float bz  = b_ih[64 + g] + b_hh[64 + g] + degf * vfold[64 + g];
        float bin = b_ih[128 + g] + degf * vfold[128 + g];
        float bhn = b_hh[128 + g];
        float gr = tile ? acc1[nt][r]     : acc0[nt][r];
        float gz = tile ? acc1[nt + 4][r] : acc0[nt + 4][r];
        float gn = tile ? acc1[nt + 8][r] : acc0[nt + 8][r];
        float hn = tile ? aN1[nt][r]      : aN0[nt][r];
        float rr = sigf(gr + br);
        float zz = sigf(gz + bz);
        float nn = tanhf(gn + bin + rr * (hn + bhn));
        float h_old = recon(Hh[o], Hl[o]);
        float hv = (1.f - zz) * nn + zz * h_old;
        unsigned short hi, lo; split2(hv, hi, lo);
        nph[o] = hi; npl[o] = lo;
      }
    }
  }
}

// ---------------------------------------------------------------------------
// CSR build v3: two-level bucket sort by dst.
// ---------------------------------------------------------------------------
__global__ __launch_bounds__(256) void k_bucket(const int* __restrict__ eidx,
                                                int* __restrict__ gcur,     // [NB*16]
                                                int* __restrict__ payload) {// [NB*BCAP]
  __shared__ int lcnt[NB];
  __shared__ int lcur[NB];
  int t = threadIdx.x;
  int e0 = blockIdx.x * 4096;
  lcnt[t] = 0;
  __syncthreads();
  int ds[16], ss[16];
#pragma unroll
  for (int i = 0; i < 16; ++i) {
    int e = e0 + i * 256 + t;
    ds[i] = eidx[Ne + e];
    ss[i] = eidx[e];
    atomicAdd(&lcnt[ds[i] >> 8], 1);
  }
  __syncthreads();
  lcur[t] = atomicAdd(&gcur[t * 16], lcnt[t]);  // reserve contiguous run
  __syncthreads();
#pragma unroll
  for (int i = 0; i < 16; ++i) {
    int b = ds[i] >> 8;
    int p = atomicAdd(&lcur[b], 1);
    if (p < BCAP) payload[b * BCAP + p] = (ss[i] << 8) | (ds[i] & 255);
  }
}

// One block per bucket: inline scan of gcur -> base, LDS hist -> rp slice,
// place srcs via LDS cursors (scatter window owned by one CU).
__global__ __launch_bounds__(256) void k_placeB(const int* __restrict__ gcur,
                                                const int* __restrict__ payload,
                                                int* __restrict__ rp,
                                                int* __restrict__ srcs) {
  __shared__ int sAll[NB];
  __shared__ int hst[NB];
  __shared__ int cur[NB];
  int b = blockIdx.x, t = threadIdx.x;
  sAll[t] = gcur[t * 16];
  hst[t] = 0;
  __syncthreads();
  int cnt = min(sAll[b], BCAP);
  for (int off = 1; off < NB; off <<= 1) {
    int v = (t >= off) ? sAll[t - off] : 0;
    __syncthreads();
    sAll[t] += v;
    __syncthreads();
  }
  int base = sAll[b] - gcur[b * 16];  // exclusive prefix (true counts)
  const int* pay = &payload[b * BCAP];
  for (int i = t; i < cnt; i += 256) atomicAdd(&hst[pay[i] & 255], 1);
  __syncthreads();
  int c = hst[t];
  cur[t] = c;
  __syncthreads();
  for (int off = 1; off < NB; off <<= 1) {
    int v = (t >= off) ? cur[t - off] : 0;
    __syncthreads();
    cur[t] += v;
    __syncthreads();
  }
  int excl = cur[t] - c;
  rp[b * 256 + t] = base + excl;
  cur[t] = base + excl;
  __syncthreads();
  for (int i = t; i < cnt; i += 256) {
    int pl = pay[i];
    int p = atomicAdd(&cur[pl & 255], 1);
    srcs[p] = pl >> 8;
  }
}

// ---------------------------------------------------------------------------
// Fused Set2Set v3: all 3 iterations + head, ONE launch, 1024 threads/block
// (16 waves).  Grid is fixed at 256 blocks (1/CU) -> go wide instead: 4x the
// waves cuts the serial attention trip counts 4x and lifts occupancy
// 12.5% -> 50%.  State lives in LDS across iterations.
// ---------------------------------------------------------------------------
constexpr int ACAP = 1024;  // max nodes per graph (dataset max ~330)
__global__ __launch_bounds__(1024) void k_s2s(const unsigned short* __restrict__ hph,
                                              const unsigned short* __restrict__ hpl,
                                              const int* __restrict__ gp,
                                              const float* __restrict__ WihT,
                                              const float* __restrict__ WhhT,
                                              const float* __restrict__ b_ih,
                                              const float* __restrict__ b_hh,
                                              const float* __restrict__ W1T,
                                              const float* __restrict__ b1,
                                              const float* __restrict__ W2,
                                              const float* __restrict__ b2,
                                              float* __restrict__ outp) {
  int g = blockIdx.x;
  int t = threadIdx.x;
  int w = t >> 6, lane = t & 63;
  __shared__ float qstar_s[128];  // [q | r] carried across iterations
  __shared__ float hs[64], cs[64], gates[256];
  __shared__ float eL[ACAP];
  __shared__ float red[16];
  __shared__ float partial[16][64];
  __shared__ float asum_p[16];
  __shared__ float emax_sh;
  __shared__ float l4[4];
  __shared__ float hid[64];

  if (t < 128) qstar_s[t] = 0.f;
  if (t < 64) { hs[t] = 0.f; cs[t] = 0.f; }
  int s = gp[g], e = gp[g + 1];
  int cnt = e - s;

  for (int it = 0; it < 3; ++it) {
    __syncthreads();   // state from init / previous iteration visible

    // ---- LSTM cell (first 4 waves) ----
    if (t < 256) {
      float acc = b_ih[t] + b_hh[t];
      for (int k = 0; k < 128; ++k) acc = fmaf(WihT[k * 256 + t], qstar_s[k], acc);
      for (int k = 0; k < 64; ++k)  acc = fmaf(WhhT[k * 256 + t], hs[k], acc);
      gates[t] = acc;
    }
    __syncthreads();
    if (t < 64) {
      float ig = sigf(gates[t]),        fg = sigf(gates[64 + t]);
      float gg = tanhf(gates[128 + t]), og = sigf(gates[192 + t]);
      float c = fg * cs[t] + ig * gg;
      float q = og * tanhf(c);
      cs[t] = c;
      hs[t] = q;
      qstar_s[t] = q;
    }
    __syncthreads();

    // ---- attention phase A: e_i = h[i].q  (16 nodes per block-iter x16 waves)
    int c4 = (lane & 15) * 4;
    float4 qv = {qstar_s[c4], qstar_s[c4 + 1], qstar_s[c4 + 2], qstar_s[c4 + 3]};
    for (int i0 = s + w * 4; i0 < e; i0 += 64) {
      int node = i0 + (lane >> 4);
      float p = 0.f;
      if (node < e) {
        ushort4 h4  = *(const ushort4*)&hph[(size_t)node * 64 + c4];
        ushort4 l4v = *(const ushort4*)&hpl[(size_t)node * 64 + c4];
        p = recon(h4.x, l4v.x) * qv.x + recon(h4.y, l4v.y) * qv.y +
            recon(h4.z, l4v.z) * qv.z + recon(h4.w, l4v.w) * qv.w;
      }
      p += __shfl_xor(p, 1); p += __shfl_xor(p, 2);
      p += __shfl_xor(p, 4); p += __shfl_xor(p, 8);
      if (node < e && (lane & 15) == 0) eL[node - s] = p;
    }
    __syncthreads();

    // ---- phase B: segment max ----
    float m = -INFINITY;
    for (int i = t; i < cnt; i += 1024) m = fmaxf(m, eL[i]);
#pragma unroll
    for (int o = 32; o >= 1; o >>= 1) m = fmaxf(m, __shfl_xor(m, o));
    if (lane == 0) red[w] = m;
    __syncthreads();
    if (t == 0) {
      float mm = -INFINITY;
      for (int q = 0; q < 16; ++q) mm = fmaxf(mm, red[q]);
      emax_sh = isfinite(mm) ? mm : 0.f;
    }
    __syncthreads();
    float emax = emax_sh;

    // ---- phase C: softmax-weighted feature sum ----
    float acc = 0.f, asum = 0.f;
    for (int i = s + w; i < e; i += 16) {
      float a = expf(eL[i - s] - emax);
      asum += a;
      float hv = recon(hph[(size_t)i * 64 + lane], hpl[(size_t)i * 64 + lane]);
      acc = fmaf(a, hv, acc);
    }
    partial[w][lane] = acc;
    if (lane == 0) asum_p[w] = asum;
    __syncthreads();
    if (t < 64) {
      float r = 0.f, as = 0.f;
      for (int q = 0; q < 16; ++q) { r += partial[q][t]; as += asum_p[q]; }
      float rv = (cnt > 0) ? r / fmaxf(as, 1e-16f) : 0.f;
      qstar_s[64 + t] = rv;
    }
  }
  __syncthreads();

  // ---- head ----
  if (t < 64) {
    float a1 = b1[t];
    for (int k = 0; k < 64; ++k)   a1 = fmaf(W1T[k * 64 + t], qstar_s[k], a1);
    for (int k = 64; k < 128; ++k) a1 = fmaf(W1T[k * 64 + t], qstar_s[k], a1);
    hid[t] = fmaxf(a1, 0.f);
  }
  __syncthreads();
  if (t < 4) {
    float lg = b2[t];
    for (int d = 0; d < 64; ++d) lg = fmaf(W2[t * 64 + d], hid[d], lg);
    l4[t] = lg;
  }
  __syncthreads();
  if (t < 4) {
    float mx = fmaxf(fmaxf(l4[0], l4[1]), fmaxf(l4[2], l4[3]));
    float ssum = expf(l4[0] - mx) + expf(l4[1] - mx) + expf(l4[2] - mx) + expf(l4[3] - mx);
    outp[g * 4 + t] = l4[t] - mx - logf(ssum);
  }
}

// ---------------------------------------------------------------------------
extern "C" void kernel_launch(void* const* d_in, const int* in_sizes, int n_in,
                              void* d_out, int out_size, void* d_ws, size_t ws_size,
                              hipStream_t stream) {
  const float* x        = (const float*)d_in[0];
  const int*   eidx     = (const int*)d_in[1];
  const int*   batch    = (const int*)d_in[2];
  const float* W_mlp    = (const float*)d_in[3];
  const float* b_mlp    = (const float*)d_in[4];
  const float* W_conv   = (const float*)d_in[5];
  const float* b_conv   = (const float*)d_in[6];
  const float* gW_ih    = (const float*)d_in[7];
  const float* gW_hh    = (const float*)d_in[8];
  const float* gb_ih    = (const float*)d_in[9];
  const float* gb_hh    = (const float*)d_in[10];
  const float* lW_ih    = (const float*)d_in[11];
  const float* lW_hh    = (const float*)d_in[12];
  const float* lb_ih    = (const float*)d_in[13];
  const float* lb_hh    = (const float*)d_in[14];
  const float* W1       = (const float*)d_in[15];
  const float* b1       = (const float*)d_in[16];
  const float* W2       = (const float*)d_in[17];
  const float* b2       = (const float*)d_in[18];
  float* outp = (float*)d_out;

  // ---- workspace layout ----
  char* ws = (char*)d_ws;
  size_t off = 0;
  auto alloc = [&](size_t bytes) { size_t r = off; off = (off + bytes + 255) & ~(size_t)255; return r; };
  unsigned short* hpAh = (unsigned short*)(ws + alloc((size_t)Nn * 64 * 2));
  unsigned short* hpAl = (unsigned short*)(ws + alloc((size_t)Nn * 64 * 2));
  unsigned short* hpBh = (unsigned short*)(ws + alloc((size_t)Nn * 64 * 2));
  unsigned short* hpBl = (unsigned short*)(ws + alloc((size_t)Nn * 64 * 2));
  unsigned short* Aih  = (unsigned short*)(ws + alloc((size_t)Nn * 96 * 2));
  unsigned short* Ail  = (unsigned short*)(ws + alloc((size_t)Nn * 96 * 2));
  unsigned short* Sh   = (unsigned short*)(ws + alloc((size_t)Nn * 64 * 2));
  unsigned short* Sl   = (unsigned short*)(ws + alloc((size_t)Nn * 64 * 2));
  int*   rp    = (int*)(ws + alloc((size_t)(Nn + 1) * 4));
  int*   srcs  = (int*)(ws + alloc((size_t)Ne * 4));
  int*   gcur  = (int*)(ws + alloc((size_t)NB * 16 * 4));
  int*   payload = (int*)(ws + alloc((size_t)NB * BCAP * 4));
  int*   gp    = (int*)(ws + alloc((size_t)(Bg + 1) * 4));
  float* WihT  = (float*)(ws + alloc((size_t)128 * 256 * 4));
  float* WhhT  = (float*)(ws + alloc((size_t)64 * 256 * 4));
  float* W1T   = (float*)(ws + alloc((size_t)128 * 64 * 4));
  float* vfold = (float*)(ws + alloc(192 * 4));
  unsigned short* mlp_h = (unsigned short*)(ws + alloc(2048 * 2));
  unsigned short* mlp_l = (unsigned short*)(ws + alloc(2048 * 2));
  unsigned short* gw_h  = (unsigned short*)(ws + alloc(30720 * 2));
  unsigned short* gw_l  = (unsigned short*)(ws + alloc(30720 * 2));
  (void)in_sizes; (void)n_in; (void)out_size; (void)ws_size;

  hipMemsetAsync(gcur, 0, (size_t)NB * 16 * 4, stream);

  // CSR build (bucket sort) + prep (incl. W_conv folding)
  k_bucket<<<Ne / 4096, 256, 0, stream>>>(eidx, gcur, payload);
  k_placeB<<<NB, 256, 0, stream>>>(gcur, payload, rp, srcs);
  k_prepw<<<355, 256, 0, stream>>>(W_mlp, W_conv, gW_ih, gW_hh, b_conv,
                                   lW_ih, lW_hh, W1,
                                   mlp_h, mlp_l, gw_h, gw_l,
                                   WihT, WhhT, W1T, vfold, batch, gp, rp);

  // conv1 (+ x-column planes)
  k_conv1<<<Nn / 64, 256, 0, stream>>>(x, mlp_h, mlp_l, b_mlp, hpAh, hpAl, Aih, Ail);

  unsigned short *cph = hpAh, *cpl = hpAl, *nph = hpBh, *npl = hpBl;
  for (int step = 0; step < 2; ++step) {
    k_aggr<<<Nn / 4, 256, 0, stream>>>(cph, rp, srcs, Sh, Sl);
    k_gru<<<Nn / 128, 256, 0, stream>>>(Aih, Ail, cph, cpl, Sh, Sl, gw_h, gw_l,
                                        gb_ih, gb_hh, vfold, rp, nph, npl);
    unsigned short* tu;
    tu = cph; cph = nph; nph = tu;
    tu = cpl; cpl = npl; npl = tu;
  }

  // Set2Set: all 3 iterations + head, one launch, 1024 threads
  k_s2s<<<Bg, 1024, 0, stream>>>(cph, cpl, gp, WihT, WhhT,
                                 lb_ih, lb_hh, W1T, b1, W2, b2, outp);
}

// Round 5
// 309.806 us; speedup vs baseline: 1.2992x; 1.2992x over previous
//
#include <hip/hip_runtime.h>
#include <math.h>

constexpr int Nn  = 65536;    // nodes
constexpr int Ne  = 1048576;  // edges
constexpr int Bg  = 256;      // graphs
constexpr int DIN = 32;
constexpr int D   = 64;

constexpr int NB   = 256;     // dst buckets (dst>>8)
constexpr int BCAP = 6144;    // bucket stream capacity (mean 4096, +36 sigma)

typedef __attribute__((ext_vector_type(8))) short bf16x8;
typedef __attribute__((ext_vector_type(8))) unsigned short u16x8;
typedef __attribute__((ext_vector_type(4))) float f32x4;

__device__ __forceinline__ float sigf(float x) { return 1.0f / (1.0f + expf(-x)); }

// ---- bf16 split helpers (RNE) ----
__device__ __forceinline__ unsigned short bf16_rne(float f) {
  unsigned u = __float_as_uint(f);
  unsigned r = u + 0x7FFFu + ((u >> 16) & 1u);
  return (unsigned short)(r >> 16);
}
__device__ __forceinline__ float bf16_tof(unsigned short h) {
  return __uint_as_float(((unsigned)h) << 16);
}
__device__ __forceinline__ void split2(float f, unsigned short& hi, unsigned short& lo) {
  hi = bf16_rne(f);
  lo = bf16_rne(f - bf16_tof(hi));
}
__device__ __forceinline__ float recon(unsigned short hi, unsigned short lo) {
  return bf16_tof(hi) + bf16_tof(lo);
}

#define MFMA(a, b, c) __builtin_amdgcn_mfma_f32_16x16x32_bf16(a, b, c, 0, 0, 0)

// ---------------------------------------------------------------------------
// Prep.  GRU weights chunk-major (5 chunks x 12nt x 64lane x 8j / plane):
//   chunks 0,1 = Wfold = Wih[:, :64] @ W_conv   (fused conv-linear)
//   chunk  2   = Wih[:, 64:96]  (x part)
//   chunks 3,4 = Whh
// Also: W_mlp pack, LSTM/W1 transposes, graphptr, rp[Nn], vfold.
// ---------------------------------------------------------------------------
__global__ void k_prepw(const float* __restrict__ W_mlp, const float* __restrict__ W_conv,
                        const float* __restrict__ gWih, const float* __restrict__ gWhh,
                        const float* __restrict__ b_conv,
                        const float* __restrict__ lW_ih, const float* __restrict__ lW_hh,
                        const float* __restrict__ W1,
                        unsigned short* __restrict__ mlp_h, unsigned short* __restrict__ mlp_l,
                        unsigned short* __restrict__ gw_h,  unsigned short* __restrict__ gw_l,
                        float* __restrict__ WihT, float* __restrict__ WhhT,
                        float* __restrict__ W1T, float* __restrict__ vfold,
                        const int* __restrict__ batch, int* __restrict__ gp,
                        int* __restrict__ rp) {
  int idx = blockIdx.x * 256 + threadIdx.x;
  if (idx < 30720) {  // GRU weights, chunk-major
    int c = idx / 6144, rem = idx % 6144;
    int nt = rem >> 9, lane = (rem >> 3) & 63, j = rem & 7;
    int n = nt * 16 + (lane & 15);
    int kk = c * 32 + (lane >> 4) * 8 + j;   // for c<3: k index into [S|x]
    float v;
    if (c < 2) {        // Wfold[n][kk] = sum_o Wih[n][o] * W_conv[o][kk]
      float s = 0.f;
      for (int o = 0; o < 64; ++o) s = fmaf(gWih[n * 96 + o], W_conv[o * 64 + kk], s);
      v = s;
    } else if (c == 2) {
      v = gWih[n * 96 + kk];                 // kk in 64..95 (x columns)
    } else {
      v = gWhh[n * 64 + (c - 3) * 32 + (lane >> 4) * 8 + j];
    }
    unsigned short hi, lo; split2(v, hi, lo);
    gw_h[idx] = hi; gw_l[idx] = lo;
    return;
  }
  if (idx < 32768) {  // W_mlp (KS=1)
    int lp = idx - 30720;
    int nt = lp >> 9, lane = (lp >> 3) & 63, j = lp & 7;
    int n = nt * 16 + (lane & 15);
    unsigned short hi, lo;
    split2(W_mlp[n * 32 + (lane >> 4) * 8 + j], hi, lo);
    mlp_h[lp] = hi; mlp_l[lp] = lo;
    return;
  }
  int t = idx - 32768;
  if (t < 32768) {                 // lstm W_ih [256][128] -> WihT [128][256]
    int row = t / 128, k = t % 128;
    WihT[k * 256 + row] = lW_ih[t];
  } else if (t < 49152) {          // lstm W_hh [256][64] -> WhhT [64][256]
    int j = t - 32768;
    int row = j / 64, k = j % 64;
    WhhT[k * 256 + row] = lW_hh[j];
  } else if (t < 57344) {          // W1 [64][128] -> W1T [128][64]
    int j = t - 49152;
    int row = j / 128, k = j % 128;
    W1T[k * 64 + row] = W1[j];
  } else if (t < 57344 + Bg + 1) { // graphptr + rp[Nn]
    int g = t - 57344;
    if (g == 0) rp[Nn] = Ne;
    int lo = 0, hi = Nn;
    while (lo < hi) {
      int mid = (lo + hi) >> 1;
      if (batch[mid] < g) lo = mid + 1; else hi = mid;
    }
    gp[g] = lo;
  } else if (t < 57344 + 257 + 192) { // vfold[192]
    int g = t - 57344 - 257;
    float s = 0.f;
    for (int o = 0; o < 64; ++o) s = fmaf(gWih[g * 96 + o], b_conv[o], s);
    vfold[g] = s;
  }
}

// ---------------------------------------------------------------------------
// conv1: h = x @ W_mlp^T + b  (K=32, N=64). Splits x in-kernel; also fills
// inp96 x-columns (64..95).  h stored as planes only.
// ---------------------------------------------------------------------------
__global__ __launch_bounds__(256) void k_conv1(const float* __restrict__ x,
                                               const unsigned short* __restrict__ Wh,
                                               const unsigned short* __restrict__ Wl,
                                               const float* __restrict__ bias,
                                               unsigned short* __restrict__ hph,
                                               unsigned short* __restrict__ hpl,
                                               unsigned short* __restrict__ Aih,
                                               unsigned short* __restrict__ Ail) {
  int wave = threadIdx.x >> 6, lane = threadIdx.x & 63;
  int quad = lane >> 4;
  int n0w = blockIdx.x * 64 + wave * 16;
  int rowA = n0w + (lane & 15);
  const float4* xp = (const float4*)&x[(size_t)rowA * 32 + quad * 8];
  float4 xa = xp[0], xb = xp[1];
  float xv[8] = {xa.x, xa.y, xa.z, xa.w, xb.x, xb.y, xb.z, xb.w};
  bf16x8 ah, al;
#pragma unroll
  for (int j = 0; j < 8; ++j) {
    unsigned short hi, lo; split2(xv[j], hi, lo);
    ah[j] = (short)hi; al[j] = (short)lo;
  }
  *(bf16x8*)&Aih[(size_t)rowA * 96 + 64 + quad * 8] = ah;
  *(bf16x8*)&Ail[(size_t)rowA * 96 + 64 + quad * 8] = al;

  f32x4 acc[4] = {};
#pragma unroll
  for (int nt = 0; nt < 4; ++nt) {
    bf16x8 bh = *(const bf16x8*)&Wh[(nt * 64 + lane) * 8];
    bf16x8 bl = *(const bf16x8*)&Wl[(nt * 64 + lane) * 8];
    acc[nt] = MFMA(ah, bh, acc[nt]);
    acc[nt] = MFMA(ah, bl, acc[nt]);
    acc[nt] = MFMA(al, bh, acc[nt]);
  }
  int col0 = lane & 15;
#pragma unroll
  for (int nt = 0; nt < 4; ++nt) {
    float bv = bias[nt * 16 + col0];
#pragma unroll
    for (int r = 0; r < 4; ++r) {
      int node = n0w + quad * 4 + r;
      float v = acc[nt][r] + bv;
      size_t o = (size_t)node * 64 + nt * 16 + col0;
      unsigned short hi, lo; split2(v, hi, lo);
      hph[o] = hi; hpl[o] = lo;
    }
  }
}

// ---------------------------------------------------------------------------
// Aggregate v4: one wave per node; lane l owns edge-slot (l>>3) and columns
// (l&7)*8..+7.  Each load instruction is u16x8 (16 B/lane, 1 KB/wave) and
// covers 8 EDGES at once -> 8x fewer gather instructions than v3, no shfl
// broadcast chain, 16 lines in flight per wave (2-deep unroll).  Edge-slot
// partial sums are combined by a fixed-order xor-shuffle tree.
// ---------------------------------------------------------------------------
__global__ __launch_bounds__(256) void k_aggr(const unsigned short* __restrict__ Hh,
                                              const int* __restrict__ rp,
                                              const int* __restrict__ srcs,
                                              unsigned short* __restrict__ Sh,
                                              unsigned short* __restrict__ Sl) {
  int wave = threadIdx.x >> 6, lane = threadIdx.x & 63;
  int node = blockIdx.x * 4 + wave;
  int s = rp[node], e = rp[node + 1];
  int n = e - s;
  const int* sp = srcs + s;
  int col8 = (lane & 7) * 8;
  int eslot = lane >> 3;
  float acc8[8] = {};
  int k = 0;
  for (; k + 16 <= n; k += 16) {
    int sA = sp[k + eslot];
    int sB = sp[k + 8 + eslot];
    u16x8 a = *(const u16x8*)&Hh[(size_t)sA * 64 + col8];
    u16x8 b = *(const u16x8*)&Hh[(size_t)sB * 64 + col8];
#pragma unroll
    for (int j = 0; j < 8; ++j) acc8[j] += bf16_tof(a[j]);
#pragma unroll
    for (int j = 0; j < 8; ++j) acc8[j] += bf16_tof(b[j]);
  }
  for (; k < n; k += 8) {
    if (k + eslot < n) {
      int sA = sp[k + eslot];
      u16x8 a = *(const u16x8*)&Hh[(size_t)sA * 64 + col8];
#pragma unroll
      for (int j = 0; j < 8; ++j) acc8[j] += bf16_tof(a[j]);
    }
  }
  // combine the 8 edge-slot partials (fixed-order tree over lanes l^8,l^16,l^32)
#pragma unroll
  for (int m = 8; m <= 32; m <<= 1) {
#pragma unroll
    for (int j = 0; j < 8; ++j) acc8[j] += __shfl_xor(acc8[j], m);
  }
  if (lane < 8) {
    u16x8 hv, lv;
#pragma unroll
    for (int j = 0; j < 8; ++j) {
      unsigned short hi, lo; split2(acc8[j], hi, lo);
      hv[j] = hi; lv[j] = lo;
    }
    *(u16x8*)&Sh[(size_t)node * 64 + col8] = hv;
    *(u16x8*)&Sl[(size_t)node * 64 + col8] = lv;
  }
}

// ---------------------------------------------------------------------------
// Fused GRU v9: gather moved out to k_aggr; chunks 0,1 read the S planes
// (Sh/Sl) exactly like the Whh chunks read Hh/Hl.  Keeps the proven
// 5-chunk double-buffered-LDS K-loop and epilogue.
// ---------------------------------------------------------------------------
__global__ __launch_bounds__(256, 2) void k_gru(const unsigned short* __restrict__ Aih,
                                                const unsigned short* __restrict__ Ail,
                                                const unsigned short* __restrict__ Hh,
                                                const unsigned short* __restrict__ Hl,
                                                const unsigned short* __restrict__ Sh,
                                                const unsigned short* __restrict__ Sl,
                                                const unsigned short* __restrict__ gw_h,
                                                const unsigned short* __restrict__ gw_l,
                                                const float* __restrict__ b_ih,
                                                const float* __restrict__ b_hh,
                                                const float* __restrict__ vfold,
                                                const int* __restrict__ rp,
                                                unsigned short* __restrict__ nph,
                                                unsigned short* __restrict__ npl) {
  __shared__ unsigned short sW[2][12288];  // per buf: hi[0..6143] | lo[6144..]
  int tid = threadIdx.x;
  int wave = tid >> 6, lane = tid & 63;
  int quad = lane >> 4;
  int n0w = blockIdx.x * 128 + wave * 32;
  int rowA0 = n0w + (lane & 15);          // tile0 A-row; tile1 = +16

  f32x4 acc0[12] = {}, acc1[12] = {};     // gi r,z,n (gh r,z folded into 0..7)
  f32x4 aN0[4] = {}, aN1[4] = {};         // gh n-gate

  // prologue: weights chunk 0
  bf16x8 gvh[3], gvl[3];
#pragma unroll
  for (int j = 0; j < 3; ++j) {
    gvh[j] = *(const bf16x8*)&gw_h[(tid + j * 256) * 8];
    gvl[j] = *(const bf16x8*)&gw_l[(tid + j * 256) * 8];
  }
#pragma unroll
  for (int j = 0; j < 3; ++j) {
    *(bf16x8*)&sW[0][(tid + j * 256) * 8] = gvh[j];
    *(bf16x8*)&sW[0][6144 + (tid + j * 256) * 8] = gvl[j];
  }
  __syncthreads();

#pragma unroll
  for (int c = 0; c < 5; ++c) {
    const int buf = c & 1;
    if (c < 4) {  // prefetch chunk c+1 weights
#pragma unroll
      for (int j = 0; j < 3; ++j) {
        gvh[j] = *(const bf16x8*)&gw_h[(c + 1) * 6144 + (tid + j * 256) * 8];
        gvl[j] = *(const bf16x8*)&gw_l[(c + 1) * 6144 + (tid + j * 256) * 8];
      }
    }
    // A fragments
    bf16x8 a0h, a0l, a1h, a1l;
    if (c < 2) {            // aggregated S planes from k_aggr
      size_t b0 = (size_t)rowA0 * 64 + c * 32 + quad * 8;
      size_t b1 = (size_t)(rowA0 + 16) * 64 + c * 32 + quad * 8;
      a0h = *(const bf16x8*)&Sh[b0]; a0l = *(const bf16x8*)&Sl[b0];
      a1h = *(const bf16x8*)&Sh[b1]; a1l = *(const bf16x8*)&Sl[b1];
    } else if (c == 2) {    // x columns from conv1 prep
      size_t b0 = (size_t)rowA0 * 96 + 64 + quad * 8;
      size_t b1 = (size_t)(rowA0 + 16) * 96 + 64 + quad * 8;
      a0h = *(const bf16x8*)&Aih[b0]; a0l = *(const bf16x8*)&Ail[b0];
      a1h = *(const bf16x8*)&Aih[b1]; a1l = *(const bf16x8*)&Ail[b1];
    } else {                // h planes (Whh chunks)
      size_t b0 = (size_t)rowA0 * 64 + (c - 3) * 32 + quad * 8;
      size_t b1 = (size_t)(rowA0 + 16) * 64 + (c - 3) * 32 + quad * 8;
      a0h = *(const bf16x8*)&Hh[b0]; a0l = *(const bf16x8*)&Hl[b0];
      a1h = *(const bf16x8*)&Hh[b1]; a1l = *(const bf16x8*)&Hl[b1];
    }
    const unsigned short* sw = sW[buf];
#pragma unroll
    for (int nt = 0; nt < 12; ++nt) {
      bf16x8 bh = *(const bf16x8*)&sw[(nt * 64 + lane) * 8];
      bf16x8 bl = *(const bf16x8*)&sw[6144 + (nt * 64 + lane) * 8];
      if (c < 3 || nt < 8) {
        acc0[nt] = MFMA(a0h, bh, acc0[nt]);
        acc0[nt] = MFMA(a0h, bl, acc0[nt]);
        acc0[nt] = MFMA(a0l, bh, acc0[nt]);
        acc1[nt] = MFMA(a1h, bh, acc1[nt]);
        acc1[nt] = MFMA(a1h, bl, acc1[nt]);
        acc1[nt] = MFMA(a1l, bh, acc1[nt]);
      } else {
        aN0[nt - 8] = MFMA(a0h, bh, aN0[nt - 8]);
        aN0[nt - 8] = MFMA(a0h, bl, aN0[nt - 8]);
        aN0[nt - 8] = MFMA(a0l, bh, aN0[nt - 8]);
        aN1[nt - 8] = MFMA(a1h, bh, aN1[nt - 8]);
        aN1[nt - 8] = MFMA(a1h, bl, aN1[nt - 8]);
        aN1[nt - 8] = MFMA(a1l, bh, aN1[nt - 8]);
      }
    }
    if (c < 4) {
#pragma unroll
      for (int j = 0; j < 3; ++j) {
        *(bf16x8*)&sW[1 - buf][(tid + j * 256) * 8] = gvh[j];
        *(bf16x8*)&sW[1 - buf][6144 + (tid + j * 256) * 8] = gvl[j];
      }
    }
    __syncthreads();
  }

  // epilogue: GRU nonlinearity + deg*vfold (folded conv bias) + plane store
  int col0 = lane & 15;
#pragma unroll
  for (int tile = 0; tile < 2; ++tile) {
    int nb = n0w + tile * 16;
#pragma unroll
    for (int r = 0; r < 4; ++r) {
      int node = nb + quad * 4 + r;
      float degf = (float)(rp[node + 1] - rp[node]);
#pragma unroll
      for (int nt = 0; nt < 4; ++nt) {
        int g = nt * 16 + col0;
        size_t o = (size_t)node * 64 + g;
        float br  = b_ih[g] + b_hh[g] + degf * vfold[g];
        float bz  = b_ih[64 + g] + b_hh[64 + g] + degf * vfold[64 + g];
        float bin = b_ih[128 + g] + degf * vfold[128 + g];
        float bhn = b_hh[128 + g];
        float gr = tile ? acc1[nt][r]     : acc0[nt][r];
        float gz = tile ? acc1[nt + 4][r] : acc0[nt + 4][r];
        float gn = tile ? acc1[nt + 8][r] : acc0[nt + 8][r];
        float hn = tile ? aN1[nt][r]      : aN0[nt][r];
        float rr = sigf(gr + br);
        float zz = sigf(gz + bz);
        float nn = tanhf(gn + bin + rr * (hn + bhn));
        float h_old = recon(Hh[o], Hl[o]);
        float hv = (1.f - zz) * nn + zz * h_old;
        unsigned short hi, lo; split2(hv, hi, lo);
        nph[o] = hi; npl[o] = lo;
      }
    }
  }
}

// ---------------------------------------------------------------------------
// CSR build v3: two-level bucket sort by dst.
// ---------------------------------------------------------------------------
__global__ __launch_bounds__(256) void k_bucket(const int* __restrict__ eidx,
                                                int* __restrict__ gcur,     // [NB*16]
                                                int* __restrict__ payload) {// [NB*BCAP]
  __shared__ int lcnt[NB];
  __shared__ int lcur[NB];
  int t = threadIdx.x;
  int e0 = blockIdx.x * 4096;
  lcnt[t] = 0;
  __syncthreads();
  int ds[16], ss[16];
#pragma unroll
  for (int i = 0; i < 16; ++i) {
    int e = e0 + i * 256 + t;
    ds[i] = eidx[Ne + e];
    ss[i] = eidx[e];
    atomicAdd(&lcnt[ds[i] >> 8], 1);
  }
  __syncthreads();
  lcur[t] = atomicAdd(&gcur[t * 16], lcnt[t]);  // reserve contiguous run
  __syncthreads();
#pragma unroll
  for (int i = 0; i < 16; ++i) {
    int b = ds[i] >> 8;
    int p = atomicAdd(&lcur[b], 1);
    if (p < BCAP) payload[b * BCAP + p] = (ss[i] << 8) | (ds[i] & 255);
  }
}

// One block per bucket: inline scan of gcur -> base, LDS hist -> rp slice,
// place srcs via LDS cursors (scatter window owned by one CU).
__global__ __launch_bounds__(256) void k_placeB(const int* __restrict__ gcur,
                                                const int* __restrict__ payload,
                                                int* __restrict__ rp,
                                                int* __restrict__ srcs) {
  __shared__ int sAll[NB];
  __shared__ int hst[NB];
  __shared__ int cur[NB];
  int b = blockIdx.x, t = threadIdx.x;
  sAll[t] = gcur[t * 16];
  hst[t] = 0;
  __syncthreads();
  int cnt = min(sAll[b], BCAP);
  for (int off = 1; off < NB; off <<= 1) {
    int v = (t >= off) ? sAll[t - off] : 0;
    __syncthreads();
    sAll[t] += v;
    __syncthreads();
  }
  int base = sAll[b] - gcur[b * 16];  // exclusive prefix (true counts)
  const int* pay = &payload[b * BCAP];
  for (int i = t; i < cnt; i += 256) atomicAdd(&hst[pay[i] & 255], 1);
  __syncthreads();
  int c = hst[t];
  cur[t] = c;
  __syncthreads();
  for (int off = 1; off < NB; off <<= 1) {
    int v = (t >= off) ? cur[t - off] : 0;
    __syncthreads();
    cur[t] += v;
    __syncthreads();
  }
  int excl = cur[t] - c;
  rp[b * 256 + t] = base + excl;
  cur[t] = base + excl;
  __syncthreads();
  for (int i = t; i < cnt; i += 256) {
    int pl = pay[i];
    int p = atomicAdd(&cur[pl & 255], 1);
    srcs[p] = pl >> 8;
  }
}

// ---------------------------------------------------------------------------
// Fused Set2Set v4: all 3 iterations + head, one launch, 512 threads
// (8 waves).  v3's 1024-thread version spilled (VGPR cap 64 -> 52 MB scratch
// writes, 157 us); 512 keeps the cap at 128 (no spill) while still doubling
// v2's wave count.  Phases A and C are 2-deep unrolled so each lane keeps
// ~4 loads in flight.  State lives in LDS across iterations.
// ---------------------------------------------------------------------------
constexpr int ACAP = 1024;  // max nodes per graph (dataset max ~330)
__global__ __launch_bounds__(512) void k_s2s(const unsigned short* __restrict__ hph,
                                             const unsigned short* __restrict__ hpl,
                                             const int* __restrict__ gp,
                                             const float* __restrict__ WihT,
                                             const float* __restrict__ WhhT,
                                             const float* __restrict__ b_ih,
                                             const float* __restrict__ b_hh,
                                             const float* __restrict__ W1T,
                                             const float* __restrict__ b1,
                                             const float* __restrict__ W2,
                                             const float* __restrict__ b2,
                                             float* __restrict__ outp) {
  int g = blockIdx.x;
  int t = threadIdx.x;
  int w = t >> 6, lane = t & 63;
  __shared__ float qstar_s[128];  // [q | r] carried across iterations
  __shared__ float hs[64], cs[64], gates[256];
  __shared__ float eL[ACAP];
  __shared__ float red[8];
  __shared__ float partial[8][64];
  __shared__ float asum_p[8];
  __shared__ float emax_sh;
  __shared__ float l4[4];
  __shared__ float hid[64];

  if (t < 128) qstar_s[t] = 0.f;
  if (t < 64) { hs[t] = 0.f; cs[t] = 0.f; }
  int s = gp[g], e = gp[g + 1];
  int cnt = e - s;

  for (int it = 0; it < 3; ++it) {
    __syncthreads();   // state from init / previous iteration visible

    // ---- LSTM cell (first 4 waves) ----
    if (t < 256) {
      float acc = b_ih[t] + b_hh[t];
      for (int k = 0; k < 128; ++k) acc = fmaf(WihT[k * 256 + t], qstar_s[k], acc);
      for (int k = 0; k < 64; ++k)  acc = fmaf(WhhT[k * 256 + t], hs[k], acc);
      gates[t] = acc;
    }
    __syncthreads();
    if (t < 64) {
      float ig = sigf(gates[t]),        fg = sigf(gates[64 + t]);
      float gg = tanhf(gates[128 + t]), og = sigf(gates[192 + t]);
      float c = fg * cs[t] + ig * gg;
      float q = og * tanhf(c);
      cs[t] = c;
      hs[t] = q;
      qstar_s[t] = q;
    }
    __syncthreads();

    // ---- attention phase A: e_i = h[i].q  (8 waves x 4 nodes, 2-deep) ----
    int c4 = (lane & 15) * 4;
    float4 qv = {qstar_s[c4], qstar_s[c4 + 1], qstar_s[c4 + 2], qstar_s[c4 + 3]};
    for (int i0 = s + w * 4; i0 < e; i0 += 64) {
      int n0 = i0 + (lane >> 4);
      int n1 = n0 + 32;
      float p0 = 0.f, p1 = 0.f;
      if (n0 < e) {
        ushort4 h4  = *(const ushort4*)&hph[(size_t)n0 * 64 + c4];
        ushort4 l4v = *(const ushort4*)&hpl[(size_t)n0 * 64 + c4];
        p0 = recon(h4.x, l4v.x) * qv.x + recon(h4.y, l4v.y) * qv.y +
             recon(h4.z, l4v.z) * qv.z + recon(h4.w, l4v.w) * qv.w;
      }
      if (n1 < e) {
        ushort4 h4  = *(const ushort4*)&hph[(size_t)n1 * 64 + c4];
        ushort4 l4v = *(const ushort4*)&hpl[(size_t)n1 * 64 + c4];
        p1 = recon(h4.x, l4v.x) * qv.x + recon(h4.y, l4v.y) * qv.y +
             recon(h4.z, l4v.z) * qv.z + recon(h4.w, l4v.w) * qv.w;
      }
      p0 += __shfl_xor(p0, 1); p0 += __shfl_xor(p0, 2);
      p0 += __shfl_xor(p0, 4); p0 += __shfl_xor(p0, 8);
      p1 += __shfl_xor(p1, 1); p1 += __shfl_xor(p1, 2);
      p1 += __shfl_xor(p1, 4); p1 += __shfl_xor(p1, 8);
      if ((lane & 15) == 0) {
        if (n0 < e) eL[n0 - s] = p0;
        if (n1 < e) eL[n1 - s] = p1;
      }
    }
    __syncthreads();

    // ---- phase B: segment max ----
    float m = -INFINITY;
    for (int i = t; i < cnt; i += 512) m = fmaxf(m, eL[i]);
#pragma unroll
    for (int o = 32; o >= 1; o >>= 1) m = fmaxf(m, __shfl_xor(m, o));
    if (lane == 0) red[w] = m;
    __syncthreads();
    if (t == 0) {
      float mm = -INFINITY;
      for (int q = 0; q < 8; ++q) mm = fmaxf(mm, red[q]);
      emax_sh = isfinite(mm) ? mm : 0.f;
    }
    __syncthreads();
    float emax = emax_sh;

    // ---- phase C: softmax-weighted feature sum (stride 8, 2-deep) ----
    float acc = 0.f, asum = 0.f;
    int i = s + w;
    for (; i + 8 < e; i += 16) {
      float a0 = expf(eL[i - s] - emax);
      float a1 = expf(eL[i + 8 - s] - emax);
      float h0 = recon(hph[(size_t)i * 64 + lane], hpl[(size_t)i * 64 + lane]);
      float h1 = recon(hph[(size_t)(i + 8) * 64 + lane], hpl[(size_t)(i + 8) * 64 + lane]);
      asum += a0;
      acc = fmaf(a0, h0, acc);
      asum += a1;
      acc = fmaf(a1, h1, acc);
    }
    for (; i < e; i += 8) {
      float a = expf(eL[i - s] - emax);
      asum += a;
      float hv = recon(hph[(size_t)i * 64 + lane], hpl[(size_t)i * 64 + lane]);
      acc = fmaf(a, hv, acc);
    }
    partial[w][lane] = acc;
    if (lane == 0) asum_p[w] = asum;
    __syncthreads();
    if (t < 64) {
      float r = 0.f, as = 0.f;
      for (int q = 0; q < 8; ++q) { r += partial[q][t]; as += asum_p[q]; }
      float rv = (cnt > 0) ? r / fmaxf(as, 1e-16f) : 0.f;
      qstar_s[64 + t] = rv;
    }
  }
  __syncthreads();

  // ---- head ----
  if (t < 64) {
    float a1 = b1[t];
    for (int k = 0; k < 64; ++k)   a1 = fmaf(W1T[k * 64 + t], qstar_s[k], a1);
    for (int k = 64; k < 128; ++k) a1 = fmaf(W1T[k * 64 + t], qstar_s[k], a1);
    hid[t] = fmaxf(a1, 0.f);
  }
  __syncthreads();
  if (t < 4) {
    float lg = b2[t];
    for (int d = 0; d < 64; ++d) lg = fmaf(W2[t * 64 + d], hid[d], lg);
    l4[t] = lg;
  }
  __syncthreads();
  if (t < 4) {
    float mx = fmaxf(fmaxf(l4[0], l4[1]), fmaxf(l4[2], l4[3]));
    float ssum = expf(l4[0] - mx) + expf(l4[1] - mx) + expf(l4[2] - mx) + expf(l4[3] - mx);
    outp[g * 4 + t] = l4[t] - mx - logf(ssum);
  }
}

// ---------------------------------------------------------------------------
extern "C" void kernel_launch(void* const* d_in, const int* in_sizes, int n_in,
                              void* d_out, int out_size, void* d_ws, size_t ws_size,
                              hipStream_t stream) {
  const float* x        = (const float*)d_in[0];
  const int*   eidx     = (const int*)d_in[1];
  const int*   batch    = (const int*)d_in[2];
  const float* W_mlp    = (const float*)d_in[3];
  const float* b_mlp    = (const float*)d_in[4];
  const float* W_conv   = (const float*)d_in[5];
  const float* b_conv   = (const float*)d_in[6];
  const float* gW_ih    = (const float*)d_in[7];
  const float* gW_hh    = (const float*)d_in[8];
  const float* gb_ih    = (const float*)d_in[9];
  const float* gb_hh    = (const float*)d_in[10];
  const float* lW_ih    = (const float*)d_in[11];
  const float* lW_hh    = (const float*)d_in[12];
  const float* lb_ih    = (const float*)d_in[13];
  const float* lb_hh    = (const float*)d_in[14];
  const float* W1       = (const float*)d_in[15];
  const float* b1       = (const float*)d_in[16];
  const float* W2       = (const float*)d_in[17];
  const float* b2       = (const float*)d_in[18];
  float* outp = (float*)d_out;

  // ---- workspace layout ----
  char* ws = (char*)d_ws;
  size_t off = 0;
  auto alloc = [&](size_t bytes) { size_t r = off; off = (off + bytes + 255) & ~(size_t)255; return r; };
  unsigned short* hpAh = (unsigned short*)(ws + alloc((size_t)Nn * 64 * 2));
  unsigned short* hpAl = (unsigned short*)(ws + alloc((size_t)Nn * 64 * 2));
  unsigned short* hpBh = (unsigned short*)(ws + alloc((size_t)Nn * 64 * 2));
  unsigned short* hpBl = (unsigned short*)(ws + alloc((size_t)Nn * 64 * 2));
  unsigned short* Aih  = (unsigned short*)(ws + alloc((size_t)Nn * 96 * 2));
  unsigned short* Ail  = (unsigned short*)(ws + alloc((size_t)Nn * 96 * 2));
  unsigned short* Sh   = (unsigned short*)(ws + alloc((size_t)Nn * 64 * 2));
  unsigned short* Sl   = (unsigned short*)(ws + alloc((size_t)Nn * 64 * 2));
  int*   rp    = (int*)(ws + alloc((size_t)(Nn + 1) * 4));
  int*   srcs  = (int*)(ws + alloc((size_t)Ne * 4));
  int*   gcur  = (int*)(ws + alloc((size_t)NB * 16 * 4));
  int*   payload = (int*)(ws + alloc((size_t)NB * BCAP * 4));
  int*   gp    = (int*)(ws + alloc((size_t)(Bg + 1) * 4));
  float* WihT  = (float*)(ws + alloc((size_t)128 * 256 * 4));
  float* WhhT  = (float*)(ws + alloc((size_t)64 * 256 * 4));
  float* W1T   = (float*)(ws + alloc((size_t)128 * 64 * 4));
  float* vfold = (float*)(ws + alloc(192 * 4));
  unsigned short* mlp_h = (unsigned short*)(ws + alloc(2048 * 2));
  unsigned short* mlp_l = (unsigned short*)(ws + alloc(2048 * 2));
  unsigned short* gw_h  = (unsigned short*)(ws + alloc(30720 * 2));
  unsigned short* gw_l  = (unsigned short*)(ws + alloc(30720 * 2));
  (void)in_sizes; (void)n_in; (void)out_size; (void)ws_size;

  hipMemsetAsync(gcur, 0, (size_t)NB * 16 * 4, stream);

  // CSR build (bucket sort) + prep (incl. W_conv folding)
  k_bucket<<<Ne / 4096, 256, 0, stream>>>(eidx, gcur, payload);
  k_placeB<<<NB, 256, 0, stream>>>(gcur, payload, rp, srcs);
  k_prepw<<<355, 256, 0, stream>>>(W_mlp, W_conv, gW_ih, gW_hh, b_conv,
                                   lW_ih, lW_hh, W1,
                                   mlp_h, mlp_l, gw_h, gw_l,
                                   WihT, WhhT, W1T, vfold, batch, gp, rp);

  // conv1 (+ x-column planes)
  k_conv1<<<Nn / 64, 256, 0, stream>>>(x, mlp_h, mlp_l, b_mlp, hpAh, hpAl, Aih, Ail);

  unsigned short *cph = hpAh, *cpl = hpAl, *nph = hpBh, *npl = hpBl;
  for (int step = 0; step < 2; ++step) {
    k_aggr<<<Nn / 4, 256, 0, stream>>>(cph, rp, srcs, Sh, Sl);
    k_gru<<<Nn / 128, 256, 0, stream>>>(Aih, Ail, cph, cpl, Sh, Sl, gw_h, gw_l,
                                        gb_ih, gb_hh, vfold, rp, nph, npl);
    unsigned short* tu;
    tu = cph; cph = nph; nph = tu;
    tu = cpl; cpl = npl; npl = tu;
  }

  // Set2Set: all 3 iterations + head, one launch, 512 threads (8 waves)
  k_s2s<<<Bg, 512, 0, stream>>>(cph, cpl, gp, WihT, WhhT,
                                lb_ih, lb_hh, W1T, b1, W2, b2, outp);
}

// Round 6
// 302.418 us; speedup vs baseline: 1.3309x; 1.0244x over previous
//
#include <hip/hip_runtime.h>
#include <math.h>

constexpr int Nn  = 65536;    // nodes
constexpr int Ne  = 1048576;  // edges
constexpr int Bg  = 256;      // graphs
constexpr int DIN = 32;
constexpr int D   = 64;

constexpr int NB   = 256;     // dst buckets (dst>>8)
constexpr int BCAP = 6144;    // bucket stream capacity (mean 4096, +36 sigma)

typedef __attribute__((ext_vector_type(8))) short bf16x8;
typedef __attribute__((ext_vector_type(8))) unsigned short u16x8;
typedef __attribute__((ext_vector_type(4))) float f32x4;

__device__ __forceinline__ float sigf(float x) { return 1.0f / (1.0f + expf(-x)); }

// ---- bf16 split helpers (RNE) ----
__device__ __forceinline__ unsigned short bf16_rne(float f) {
  unsigned u = __float_as_uint(f);
  unsigned r = u + 0x7FFFu + ((u >> 16) & 1u);
  return (unsigned short)(r >> 16);
}
__device__ __forceinline__ float bf16_tof(unsigned short h) {
  return __uint_as_float(((unsigned)h) << 16);
}
__device__ __forceinline__ void split2(float f, unsigned short& hi, unsigned short& lo) {
  hi = bf16_rne(f);
  lo = bf16_rne(f - bf16_tof(hi));
}
__device__ __forceinline__ float recon(unsigned short hi, unsigned short lo) {
  return bf16_tof(hi) + bf16_tof(lo);
}

#define MFMA(a, b, c) __builtin_amdgcn_mfma_f32_16x16x32_bf16(a, b, c, 0, 0, 0)

// ---------------------------------------------------------------------------
// Prep.  GRU weights chunk-major (5 chunks x 12nt x 64lane x 8j / plane):
//   chunks 0,1 = Wfold = Wih[:, :64] @ W_conv   (fused conv-linear)
//   chunk  2   = Wih[:, 64:96]  (x part)
//   chunks 3,4 = Whh
// Also: W_mlp pack, LSTM/W1 transposes, graphptr, rp[Nn], vfold.
// ---------------------------------------------------------------------------
__global__ void k_prepw(const float* __restrict__ W_mlp, const float* __restrict__ W_conv,
                        const float* __restrict__ gWih, const float* __restrict__ gWhh,
                        const float* __restrict__ b_conv,
                        const float* __restrict__ lW_ih, const float* __restrict__ lW_hh,
                        const float* __restrict__ W1,
                        unsigned short* __restrict__ mlp_h, unsigned short* __restrict__ mlp_l,
                        unsigned short* __restrict__ gw_h,  unsigned short* __restrict__ gw_l,
                        float* __restrict__ WihT, float* __restrict__ WhhT,
                        float* __restrict__ W1T, float* __restrict__ vfold,
                        const int* __restrict__ batch, int* __restrict__ gp,
                        int* __restrict__ rp) {
  int idx = blockIdx.x * 256 + threadIdx.x;
  if (idx < 30720) {  // GRU weights, chunk-major
    int c = idx / 6144, rem = idx % 6144;
    int nt = rem >> 9, lane = (rem >> 3) & 63, j = rem & 7;
    int n = nt * 16 + (lane & 15);
    int kk = c * 32 + (lane >> 4) * 8 + j;   // for c<3: k index into [S|x]
    float v;
    if (c < 2) {        // Wfold[n][kk] = sum_o Wih[n][o] * W_conv[o][kk]
      float s = 0.f;
      for (int o = 0; o < 64; ++o) s = fmaf(gWih[n * 96 + o], W_conv[o * 64 + kk], s);
      v = s;
    } else if (c == 2) {
      v = gWih[n * 96 + kk];                 // kk in 64..95 (x columns)
    } else {
      v = gWhh[n * 64 + (c - 3) * 32 + (lane >> 4) * 8 + j];
    }
    unsigned short hi, lo; split2(v, hi, lo);
    gw_h[idx] = hi; gw_l[idx] = lo;
    return;
  }
  if (idx < 32768) {  // W_mlp (KS=1)
    int lp = idx - 30720;
    int nt = lp >> 9, lane = (lp >> 3) & 63, j = lp & 7;
    int n = nt * 16 + (lane & 15);
    unsigned short hi, lo;
    split2(W_mlp[n * 32 + (lane >> 4) * 8 + j], hi, lo);
    mlp_h[lp] = hi; mlp_l[lp] = lo;
    return;
  }
  int t = idx - 32768;
  if (t < 32768) {                 // lstm W_ih [256][128] -> WihT [128][256]
    int row = t / 128, k = t % 128;
    WihT[k * 256 + row] = lW_ih[t];
  } else if (t < 49152) {          // lstm W_hh [256][64] -> WhhT [64][256]
    int j = t - 32768;
    int row = j / 64, k = j % 64;
    WhhT[k * 256 + row] = lW_hh[j];
  } else if (t < 57344) {          // W1 [64][128] -> W1T [128][64]
    int j = t - 49152;
    int row = j / 128, k = j % 128;
    W1T[k * 64 + row] = W1[j];
  } else if (t < 57344 + Bg + 1) { // graphptr + rp[Nn]
    int g = t - 57344;
    if (g == 0) rp[Nn] = Ne;
    int lo = 0, hi = Nn;
    while (lo < hi) {
      int mid = (lo + hi) >> 1;
      if (batch[mid] < g) lo = mid + 1; else hi = mid;
    }
    gp[g] = lo;
  } else if (t < 57344 + 257 + 192) { // vfold[192]
    int g = t - 57344 - 257;
    float s = 0.f;
    for (int o = 0; o < 64; ++o) s = fmaf(gWih[g * 96 + o], b_conv[o], s);
    vfold[g] = s;
  }
}

// ---------------------------------------------------------------------------
// conv1: h = x @ W_mlp^T + b  (K=32, N=64). Splits x in-kernel; also fills
// inp96 x-columns (64..95).  h stored as planes only.
// ---------------------------------------------------------------------------
__global__ __launch_bounds__(256) void k_conv1(const float* __restrict__ x,
                                               const unsigned short* __restrict__ Wh,
                                               const unsigned short* __restrict__ Wl,
                                               const float* __restrict__ bias,
                                               unsigned short* __restrict__ hph,
                                               unsigned short* __restrict__ hpl,
                                               unsigned short* __restrict__ Aih,
                                               unsigned short* __restrict__ Ail) {
  int wave = threadIdx.x >> 6, lane = threadIdx.x & 63;
  int quad = lane >> 4;
  int n0w = blockIdx.x * 64 + wave * 16;
  int rowA = n0w + (lane & 15);
  const float4* xp = (const float4*)&x[(size_t)rowA * 32 + quad * 8];
  float4 xa = xp[0], xb = xp[1];
  float xv[8] = {xa.x, xa.y, xa.z, xa.w, xb.x, xb.y, xb.z, xb.w};
  bf16x8 ah, al;
#pragma unroll
  for (int j = 0; j < 8; ++j) {
    unsigned short hi, lo; split2(xv[j], hi, lo);
    ah[j] = (short)hi; al[j] = (short)lo;
  }
  *(bf16x8*)&Aih[(size_t)rowA * 96 + 64 + quad * 8] = ah;
  *(bf16x8*)&Ail[(size_t)rowA * 96 + 64 + quad * 8] = al;

  f32x4 acc[4] = {};
#pragma unroll
  for (int nt = 0; nt < 4; ++nt) {
    bf16x8 bh = *(const bf16x8*)&Wh[(nt * 64 + lane) * 8];
    bf16x8 bl = *(const bf16x8*)&Wl[(nt * 64 + lane) * 8];
    acc[nt] = MFMA(ah, bh, acc[nt]);
    acc[nt] = MFMA(ah, bl, acc[nt]);
    acc[nt] = MFMA(al, bh, acc[nt]);
  }
  int col0 = lane & 15;
#pragma unroll
  for (int nt = 0; nt < 4; ++nt) {
    float bv = bias[nt * 16 + col0];
#pragma unroll
    for (int r = 0; r < 4; ++r) {
      int node = n0w + quad * 4 + r;
      float v = acc[nt][r] + bv;
      size_t o = (size_t)node * 64 + nt * 16 + col0;
      unsigned short hi, lo; split2(v, hi, lo);
      hph[o] = hi; hpl[o] = lo;
    }
  }
}

// ---------------------------------------------------------------------------
// Aggregate v4: one wave per node; lane l owns edge-slot (l>>3) and columns
// (l&7)*8..+7.  Each load instruction is u16x8 (16 B/lane, 1 KB/wave) and
// covers 8 EDGES at once.  Edge-slot partials combined by fixed-order
// xor-shuffle tree.
// ---------------------------------------------------------------------------
__global__ __launch_bounds__(256) void k_aggr(const unsigned short* __restrict__ Hh,
                                              const int* __restrict__ rp,
                                              const int* __restrict__ srcs,
                                              unsigned short* __restrict__ Sh,
                                              unsigned short* __restrict__ Sl) {
  int wave = threadIdx.x >> 6, lane = threadIdx.x & 63;
  int node = blockIdx.x * 4 + wave;
  int s = rp[node], e = rp[node + 1];
  int n = e - s;
  const int* sp = srcs + s;
  int col8 = (lane & 7) * 8;
  int eslot = lane >> 3;
  float acc8[8] = {};
  int k = 0;
  for (; k + 16 <= n; k += 16) {
    int sA = sp[k + eslot];
    int sB = sp[k + 8 + eslot];
    u16x8 a = *(const u16x8*)&Hh[(size_t)sA * 64 + col8];
    u16x8 b = *(const u16x8*)&Hh[(size_t)sB * 64 + col8];
#pragma unroll
    for (int j = 0; j < 8; ++j) acc8[j] += bf16_tof(a[j]);
#pragma unroll
    for (int j = 0; j < 8; ++j) acc8[j] += bf16_tof(b[j]);
  }
  for (; k < n; k += 8) {
    if (k + eslot < n) {
      int sA = sp[k + eslot];
      u16x8 a = *(const u16x8*)&Hh[(size_t)sA * 64 + col8];
#pragma unroll
      for (int j = 0; j < 8; ++j) acc8[j] += bf16_tof(a[j]);
    }
  }
  // combine the 8 edge-slot partials (fixed-order tree over lanes l^8,l^16,l^32)
#pragma unroll
  for (int m = 8; m <= 32; m <<= 1) {
#pragma unroll
    for (int j = 0; j < 8; ++j) acc8[j] += __shfl_xor(acc8[j], m);
  }
  if (lane < 8) {
    u16x8 hv, lv;
#pragma unroll
    for (int j = 0; j < 8; ++j) {
      unsigned short hi, lo; split2(acc8[j], hi, lo);
      hv[j] = hi; lv[j] = lo;
    }
    *(u16x8*)&Sh[(size_t)node * 64 + col8] = hv;
    *(u16x8*)&Sl[(size_t)node * 64 + col8] = lv;
  }
}

// ---------------------------------------------------------------------------
// Fused GRU v9: gather moved out to k_aggr; chunks 0,1 read the S planes
// (Sh/Sl) exactly like the Whh chunks read Hh/Hl.  Keeps the proven
// 5-chunk double-buffered-LDS K-loop and epilogue.
// ---------------------------------------------------------------------------
__global__ __launch_bounds__(256, 2) void k_gru(const unsigned short* __restrict__ Aih,
                                                const unsigned short* __restrict__ Ail,
                                                const unsigned short* __restrict__ Hh,
                                                const unsigned short* __restrict__ Hl,
                                                const unsigned short* __restrict__ Sh,
                                                const unsigned short* __restrict__ Sl,
                                                const unsigned short* __restrict__ gw_h,
                                                const unsigned short* __restrict__ gw_l,
                                                const float* __restrict__ b_ih,
                                                const float* __restrict__ b_hh,
                                                const float* __restrict__ vfold,
                                                const int* __restrict__ rp,
                                                unsigned short* __restrict__ nph,
                                                unsigned short* __restrict__ npl) {
  __shared__ unsigned short sW[2][12288];  // per buf: hi[0..6143] | lo[6144..]
  int tid = threadIdx.x;
  int wave = tid >> 6, lane = tid & 63;
  int quad = lane >> 4;
  int n0w = blockIdx.x * 128 + wave * 32;
  int rowA0 = n0w + (lane & 15);          // tile0 A-row; tile1 = +16

  f32x4 acc0[12] = {}, acc1[12] = {};     // gi r,z,n (gh r,z folded into 0..7)
  f32x4 aN0[4] = {}, aN1[4] = {};         // gh n-gate

  // prologue: weights chunk 0
  bf16x8 gvh[3], gvl[3];
#pragma unroll
  for (int j = 0; j < 3; ++j) {
    gvh[j] = *(const bf16x8*)&gw_h[(tid + j * 256) * 8];
    gvl[j] = *(const bf16x8*)&gw_l[(tid + j * 256) * 8];
  }
#pragma unroll
  for (int j = 0; j < 3; ++j) {
    *(bf16x8*)&sW[0][(tid + j * 256) * 8] = gvh[j];
    *(bf16x8*)&sW[0][6144 + (tid + j * 256) * 8] = gvl[j];
  }
  __syncthreads();

#pragma unroll
  for (int c = 0; c < 5; ++c) {
    const int buf = c & 1;
    if (c < 4) {  // prefetch chunk c+1 weights
#pragma unroll
      for (int j = 0; j < 3; ++j) {
        gvh[j] = *(const bf16x8*)&gw_h[(c + 1) * 6144 + (tid + j * 256) * 8];
        gvl[j] = *(const bf16x8*)&gw_l[(c + 1) * 6144 + (tid + j * 256) * 8];
      }
    }
    // A fragments
    bf16x8 a0h, a0l, a1h, a1l;
    if (c < 2) {            // aggregated S planes from k_aggr
      size_t b0 = (size_t)rowA0 * 64 + c * 32 + quad * 8;
      size_t b1 = (size_t)(rowA0 + 16) * 64 + c * 32 + quad * 8;
      a0h = *(const bf16x8*)&Sh[b0]; a0l = *(const bf16x8*)&Sl[b0];
      a1h = *(const bf16x8*)&Sh[b1]; a1l = *(const bf16x8*)&Sl[b1];
    } else if (c == 2) {    // x columns from conv1 prep
      size_t b0 = (size_t)rowA0 * 96 + 64 + quad * 8;
      size_t b1 = (size_t)(rowA0 + 16) * 96 + 64 + quad * 8;
      a0h = *(const bf16x8*)&Aih[b0]; a0l = *(const bf16x8*)&Ail[b0];
      a1h = *(const bf16x8*)&Aih[b1]; a1l = *(const bf16x8*)&Ail[b1];
    } else {                // h planes (Whh chunks)
      size_t b0 = (size_t)rowA0 * 64 + (c - 3) * 32 + quad * 8;
      size_t b1 = (size_t)(rowA0 + 16) * 64 + (c - 3) * 32 + quad * 8;
      a0h = *(const bf16x8*)&Hh[b0]; a0l = *(const bf16x8*)&Hl[b0];
      a1h = *(const bf16x8*)&Hh[b1]; a1l = *(const bf16x8*)&Hl[b1];
    }
    const unsigned short* sw = sW[buf];
#pragma unroll
    for (int nt = 0; nt < 12; ++nt) {
      bf16x8 bh = *(const bf16x8*)&sw[(nt * 64 + lane) * 8];
      bf16x8 bl = *(const bf16x8*)&sw[6144 + (nt * 64 + lane) * 8];
      if (c < 3 || nt < 8) {
        acc0[nt] = MFMA(a0h, bh, acc0[nt]);
        acc0[nt] = MFMA(a0h, bl, acc0[nt]);
        acc0[nt] = MFMA(a0l, bh, acc0[nt]);
        acc1[nt] = MFMA(a1h, bh, acc1[nt]);
        acc1[nt] = MFMA(a1h, bl, acc1[nt]);
        acc1[nt] = MFMA(a1l, bh, acc1[nt]);
      } else {
        aN0[nt - 8] = MFMA(a0h, bh, aN0[nt - 8]);
        aN0[nt - 8] = MFMA(a0h, bl, aN0[nt - 8]);
        aN0[nt - 8] = MFMA(a0l, bh, aN0[nt - 8]);
        aN1[nt - 8] = MFMA(a1h, bh, aN1[nt - 8]);
        aN1[nt - 8] = MFMA(a1h, bl, aN1[nt - 8]);
        aN1[nt - 8] = MFMA(a1l, bh, aN1[nt - 8]);
      }
    }
    if (c < 4) {
#pragma unroll
      for (int j = 0; j < 3; ++j) {
        *(bf16x8*)&sW[1 - buf][(tid + j * 256) * 8] = gvh[j];
        *(bf16x8*)&sW[1 - buf][6144 + (tid + j * 256) * 8] = gvl[j];
      }
    }
    __syncthreads();
  }

  // epilogue: GRU nonlinearity + deg*vfold (folded conv bias) + plane store
  int col0 = lane & 15;
#pragma unroll
  for (int tile = 0; tile < 2; ++tile) {
    int nb = n0w + tile * 16;
#pragma unroll
    for (int r = 0; r < 4; ++r) {
      int node = nb + quad * 4 + r;
      float degf = (float)(rp[node + 1] - rp[node]);
#pragma unroll
      for (int nt = 0; nt < 4; ++nt) {
        int g = nt * 16 + col0;
        size_t o = (size_t)node * 64 + g;
        float br  = b_ih[g] + b_hh[g] + degf * vfold[g];
        float bz  = b_ih[64 + g] + b_hh[64 + g] + degf * vfold[64 + g];
        float bin = b_ih[128 + g] + degf * vfold[128 + g];
        float bhn = b_hh[128 + g];
        float gr = tile ? acc1[nt][r]     : acc0[nt][r];
        float gz = tile ? acc1[nt + 4][r] : acc0[nt + 4][r];
        float gn = tile ? acc1[nt + 8][r] : acc0[nt + 8][r];
        float hn = tile ? aN1[nt][r]      : aN0[nt][r];
        float rr = sigf(gr + br);
        float zz = sigf(gz + bz);
        float nn = tanhf(gn + bin + rr * (hn + bhn));
        float h_old = recon(Hh[o], Hl[o]);
        float hv = (1.f - zz) * nn + zz * h_old;
        unsigned short hi, lo; split2(hv, hi, lo);
        nph[o] = hi; npl[o] = lo;
      }
    }
  }
}

// ---------------------------------------------------------------------------
// CSR build v3: two-level bucket sort by dst.
// ---------------------------------------------------------------------------
__global__ __launch_bounds__(256) void k_bucket(const int* __restrict__ eidx,
                                                int* __restrict__ gcur,     // [NB*16]
                                                int* __restrict__ payload) {// [NB*BCAP]
  __shared__ int lcnt[NB];
  __shared__ int lcur[NB];
  int t = threadIdx.x;
  int e0 = blockIdx.x * 4096;
  lcnt[t] = 0;
  __syncthreads();
  int ds[16], ss[16];
#pragma unroll
  for (int i = 0; i < 16; ++i) {
    int e = e0 + i * 256 + t;
    ds[i] = eidx[Ne + e];
    ss[i] = eidx[e];
    atomicAdd(&lcnt[ds[i] >> 8], 1);
  }
  __syncthreads();
  lcur[t] = atomicAdd(&gcur[t * 16], lcnt[t]);  // reserve contiguous run
  __syncthreads();
#pragma unroll
  for (int i = 0; i < 16; ++i) {
    int b = ds[i] >> 8;
    int p = atomicAdd(&lcur[b], 1);
    if (p < BCAP) payload[b * BCAP + p] = (ss[i] << 8) | (ds[i] & 255);
  }
}

// One block per bucket: inline scan of gcur -> base, LDS hist -> rp slice,
// place srcs via LDS cursors (scatter window owned by one CU).
__global__ __launch_bounds__(256) void k_placeB(const int* __restrict__ gcur,
                                                const int* __restrict__ payload,
                                                int* __restrict__ rp,
                                                int* __restrict__ srcs) {
  __shared__ int sAll[NB];
  __shared__ int hst[NB];
  __shared__ int cur[NB];
  int b = blockIdx.x, t = threadIdx.x;
  sAll[t] = gcur[t * 16];
  hst[t] = 0;
  __syncthreads();
  int cnt = min(sAll[b], BCAP);
  for (int off = 1; off < NB; off <<= 1) {
    int v = (t >= off) ? sAll[t - off] : 0;
    __syncthreads();
    sAll[t] += v;
    __syncthreads();
  }
  int base = sAll[b] - gcur[b * 16];  // exclusive prefix (true counts)
  const int* pay = &payload[b * BCAP];
  for (int i = t; i < cnt; i += 256) atomicAdd(&hst[pay[i] & 255], 1);
  __syncthreads();
  int c = hst[t];
  cur[t] = c;
  __syncthreads();
  for (int off = 1; off < NB; off <<= 1) {
    int v = (t >= off) ? cur[t - off] : 0;
    __syncthreads();
    cur[t] += v;
    __syncthreads();
  }
  int excl = cur[t] - c;
  rp[b * 256 + t] = base + excl;
  cur[t] = base + excl;
  __syncthreads();
  for (int i = t; i < cnt; i += 256) {
    int pl = pay[i];
    int p = atomicAdd(&cur[pl & 255], 1);
    srcs[p] = pl >> 8;
  }
}

// ---------------------------------------------------------------------------
// Fused Set2Set v5: all 3 iterations + head, one launch, 512 threads.
// NEW: the graph's h rows (<= ~330 x 64) are reconstructed to f32 ONCE into
// dynamic LDS (112 KB; 1 block/CU so the full 160 KB LDS pool is ours).
// Phases A and C then read LDS (~10 cy) instead of global (~300-900 cy) --
// the kernel was pure exposed latency (occ 19%, VALU 19%, HBM 2%).
// Staged value = exact recon() the phases computed before -> identical math.
// LCAP=448 rows: graph sizes are Binomial(65536,1/256), mean 256 sd 16;
// 448 = +12 sigma.
// ---------------------------------------------------------------------------
constexpr int LCAP = 448;
__global__ __launch_bounds__(512) void k_s2s(const unsigned short* __restrict__ hph,
                                             const unsigned short* __restrict__ hpl,
                                             const int* __restrict__ gp,
                                             const float* __restrict__ WihT,
                                             const float* __restrict__ WhhT,
                                             const float* __restrict__ b_ih,
                                             const float* __restrict__ b_hh,
                                             const float* __restrict__ W1T,
                                             const float* __restrict__ b1,
                                             const float* __restrict__ W2,
                                             const float* __restrict__ b2,
                                             float* __restrict__ outp) {
  extern __shared__ float hL[];   // [LCAP][64] f32 staged h
  int g = blockIdx.x;
  int t = threadIdx.x;
  int w = t >> 6, lane = t & 63;
  __shared__ float qstar_s[128];  // [q | r] carried across iterations
  __shared__ float hs[64], cs[64], gates[256];
  __shared__ float eL[LCAP];
  __shared__ float red[8];
  __shared__ float partial[8][64];
  __shared__ float asum_p[8];
  __shared__ float emax_sh;
  __shared__ float l4[4];
  __shared__ float hid[64];

  if (t < 128) qstar_s[t] = 0.f;
  if (t < 64) { hs[t] = 0.f; cs[t] = 0.f; }
  int s = gp[g], e = gp[g + 1];
  int cnt = e - s;

  // ---- stage h rows once: hL[j] = recon(hph[s*64+j], hpl[s*64+j]) ----
  {
    int total = cnt * 64;
    for (int j = t * 4; j < total; j += 512 * 4) {
      ushort4 hh = *(const ushort4*)&hph[(size_t)s * 64 + j];
      ushort4 ll = *(const ushort4*)&hpl[(size_t)s * 64 + j];
      float4 v;
      v.x = recon(hh.x, ll.x); v.y = recon(hh.y, ll.y);
      v.z = recon(hh.z, ll.z); v.w = recon(hh.w, ll.w);
      *(float4*)&hL[j] = v;
    }
  }

  for (int it = 0; it < 3; ++it) {
    __syncthreads();   // state + staged hL visible

    // ---- LSTM cell (first 4 waves) ----
    if (t < 256) {
      float acc = b_ih[t] + b_hh[t];
      for (int k = 0; k < 128; ++k) acc = fmaf(WihT[k * 256 + t], qstar_s[k], acc);
      for (int k = 0; k < 64; ++k)  acc = fmaf(WhhT[k * 256 + t], hs[k], acc);
      gates[t] = acc;
    }
    __syncthreads();
    if (t < 64) {
      float ig = sigf(gates[t]),        fg = sigf(gates[64 + t]);
      float gg = tanhf(gates[128 + t]), og = sigf(gates[192 + t]);
      float c = fg * cs[t] + ig * gg;
      float q = og * tanhf(c);
      cs[t] = c;
      hs[t] = q;
      qstar_s[t] = q;
    }
    __syncthreads();

    // ---- attention phase A: e_i = h[i].q  (LDS reads) ----
    int c4 = (lane & 15) * 4;
    float4 qv = {qstar_s[c4], qstar_s[c4 + 1], qstar_s[c4 + 2], qstar_s[c4 + 3]};
    for (int i0 = s + w * 4; i0 < e; i0 += 32) {
      int node = i0 + (lane >> 4);
      float p = 0.f;
      if (node < e) {
        float4 hv = *(const float4*)&hL[(node - s) * 64 + c4];
        p = hv.x * qv.x + hv.y * qv.y + hv.z * qv.z + hv.w * qv.w;
      }
      p += __shfl_xor(p, 1); p += __shfl_xor(p, 2);
      p += __shfl_xor(p, 4); p += __shfl_xor(p, 8);
      if (node < e && (lane & 15) == 0) eL[node - s] = p;
    }
    __syncthreads();

    // ---- phase B: segment max ----
    float m = -INFINITY;
    for (int i = t; i < cnt; i += 512) m = fmaxf(m, eL[i]);
#pragma unroll
    for (int o = 32; o >= 1; o >>= 1) m = fmaxf(m, __shfl_xor(m, o));
    if (lane == 0) red[w] = m;
    __syncthreads();
    if (t == 0) {
      float mm = -INFINITY;
      for (int q = 0; q < 8; ++q) mm = fmaxf(mm, red[q]);
      emax_sh = isfinite(mm) ? mm : 0.f;
    }
    __syncthreads();
    float emax = emax_sh;

    // ---- phase C: softmax-weighted feature sum (LDS reads) ----
    float acc = 0.f, asum = 0.f;
    for (int i = s + w; i < e; i += 8) {
      float a = expf(eL[i - s] - emax);
      asum += a;
      acc = fmaf(a, hL[(i - s) * 64 + lane], acc);
    }
    partial[w][lane] = acc;
    if (lane == 0) asum_p[w] = asum;
    __syncthreads();
    if (t < 64) {
      float r = 0.f, as = 0.f;
      for (int q = 0; q < 8; ++q) { r += partial[q][t]; as += asum_p[q]; }
      float rv = (cnt > 0) ? r / fmaxf(as, 1e-16f) : 0.f;
      qstar_s[64 + t] = rv;
    }
  }
  __syncthreads();

  // ---- head ----
  if (t < 64) {
    float a1 = b1[t];
    for (int k = 0; k < 64; ++k)   a1 = fmaf(W1T[k * 64 + t], qstar_s[k], a1);
    for (int k = 64; k < 128; ++k) a1 = fmaf(W1T[k * 64 + t], qstar_s[k], a1);
    hid[t] = fmaxf(a1, 0.f);
  }
  __syncthreads();
  if (t < 4) {
    float lg = b2[t];
    for (int d = 0; d < 64; ++d) lg = fmaf(W2[t * 64 + d], hid[d], lg);
    l4[t] = lg;
  }
  __syncthreads();
  if (t < 4) {
    float mx = fmaxf(fmaxf(l4[0], l4[1]), fmaxf(l4[2], l4[3]));
    float ssum = expf(l4[0] - mx) + expf(l4[1] - mx) + expf(l4[2] - mx) + expf(l4[3] - mx);
    outp[g * 4 + t] = l4[t] - mx - logf(ssum);
  }
}

// ---------------------------------------------------------------------------
extern "C" void kernel_launch(void* const* d_in, const int* in_sizes, int n_in,
                              void* d_out, int out_size, void* d_ws, size_t ws_size,
                              hipStream_t stream) {
  const float* x        = (const float*)d_in[0];
  const int*   eidx     = (const int*)d_in[1];
  const int*   batch    = (const int*)d_in[2];
  const float* W_mlp    = (const float*)d_in[3];
  const float* b_mlp    = (const float*)d_in[4];
  const float* W_conv   = (const float*)d_in[5];
  const float* b_conv   = (const float*)d_in[6];
  const float* gW_ih    = (const float*)d_in[7];
  const float* gW_hh    = (const float*)d_in[8];
  const float* gb_ih    = (const float*)d_in[9];
  const float* gb_hh    = (const float*)d_in[10];
  const float* lW_ih    = (const float*)d_in[11];
  const float* lW_hh    = (const float*)d_in[12];
  const float* lb_ih    = (const float*)d_in[13];
  const float* lb_hh    = (const float*)d_in[14];
  const float* W1       = (const float*)d_in[15];
  const float* b1       = (const float*)d_in[16];
  const float* W2       = (const float*)d_in[17];
  const float* b2       = (const float*)d_in[18];
  float* outp = (float*)d_out;

  // ---- workspace layout ----
  char* ws = (char*)d_ws;
  size_t off = 0;
  auto alloc = [&](size_t bytes) { size_t r = off; off = (off + bytes + 255) & ~(size_t)255; return r; };
  unsigned short* hpAh = (unsigned short*)(ws + alloc((size_t)Nn * 64 * 2));
  unsigned short* hpAl = (unsigned short*)(ws + alloc((size_t)Nn * 64 * 2));
  unsigned short* hpBh = (unsigned short*)(ws + alloc((size_t)Nn * 64 * 2));
  unsigned short* hpBl = (unsigned short*)(ws + alloc((size_t)Nn * 64 * 2));
  unsigned short* Aih  = (unsigned short*)(ws + alloc((size_t)Nn * 96 * 2));
  unsigned short* Ail  = (unsigned short*)(ws + alloc((size_t)Nn * 96 * 2));
  unsigned short* Sh   = (unsigned short*)(ws + alloc((size_t)Nn * 64 * 2));
  unsigned short* Sl   = (unsigned short*)(ws + alloc((size_t)Nn * 64 * 2));
  int*   rp    = (int*)(ws + alloc((size_t)(Nn + 1) * 4));
  int*   srcs  = (int*)(ws + alloc((size_t)Ne * 4));
  int*   gcur  = (int*)(ws + alloc((size_t)NB * 16 * 4));
  int*   payload = (int*)(ws + alloc((size_t)NB * BCAP * 4));
  int*   gp    = (int*)(ws + alloc((size_t)(Bg + 1) * 4));
  float* WihT  = (float*)(ws + alloc((size_t)128 * 256 * 4));
  float* WhhT  = (float*)(ws + alloc((size_t)64 * 256 * 4));
  float* W1T   = (float*)(ws + alloc((size_t)128 * 64 * 4));
  float* vfold = (float*)(ws + alloc(192 * 4));
  unsigned short* mlp_h = (unsigned short*)(ws + alloc(2048 * 2));
  unsigned short* mlp_l = (unsigned short*)(ws + alloc(2048 * 2));
  unsigned short* gw_h  = (unsigned short*)(ws + alloc(30720 * 2));
  unsigned short* gw_l  = (unsigned short*)(ws + alloc(30720 * 2));
  (void)in_sizes; (void)n_in; (void)out_size; (void)ws_size;

  hipMemsetAsync(gcur, 0, (size_t)NB * 16 * 4, stream);

  // CSR build (bucket sort) + prep (incl. W_conv folding)
  k_bucket<<<Ne / 4096, 256, 0, stream>>>(eidx, gcur, payload);
  k_placeB<<<NB, 256, 0, stream>>>(gcur, payload, rp, srcs);
  k_prepw<<<355, 256, 0, stream>>>(W_mlp, W_conv, gW_ih, gW_hh, b_conv,
                                   lW_ih, lW_hh, W1,
                                   mlp_h, mlp_l, gw_h, gw_l,
                                   WihT, WhhT, W1T, vfold, batch, gp, rp);

  // conv1 (+ x-column planes)
  k_conv1<<<Nn / 64, 256, 0, stream>>>(x, mlp_h, mlp_l, b_mlp, hpAh, hpAl, Aih, Ail);

  unsigned short *cph = hpAh, *cpl = hpAl, *nph = hpBh, *npl = hpBl;
  for (int step = 0; step < 2; ++step) {
    k_aggr<<<Nn / 4, 256, 0, stream>>>(cph, rp, srcs, Sh, Sl);
    k_gru<<<Nn / 128, 256, 0, stream>>>(Aih, Ail, cph, cpl, Sh, Sl, gw_h, gw_l,
                                        gb_ih, gb_hh, vfold, rp, nph, npl);
    unsigned short* tu;
    tu = cph; cph = nph; nph = tu;
    tu = cpl; cpl = npl; npl = tu;
  }

  // Set2Set: all 3 iterations + head, one launch, 512 threads, 112 KB dyn LDS
  const size_t dynLds = (size_t)LCAP * 64 * sizeof(float);  // 114688 B
  static bool attr_set = false;
  if (!attr_set) {
    hipFuncSetAttribute((const void*)k_s2s,
                        hipFuncAttributeMaxDynamicSharedMemorySize,
                        (int)dynLds);
    attr_set = true;
  }
  k_s2s<<<Bg, 512, dynLds, stream>>>(cph, cpl, gp, WihT, WhhT,
                                     lb_ih, lb_hh, W1T, b1, W2, b2, outp);
}